// Round 1
// baseline (205.839 us; speedup 1.0000x reference)
//
#include <hip/hip_runtime.h>
#include <hip/hip_bf16.h>
#include <type_traits>
#include <stdint.h>

// ---- problem constants ----
static constexpr int BB   = 4;
static constexpr int SS   = 1024;
static constexpr int HH   = 32;
static constexpr int HKV  = 8;
static constexpr int GG   = 4;      // H / HKV
static constexpr int DD   = 128;
static constexpr int PAGE = 128;    // paged-cache block size
static constexpr int NBLK = 64;     // cache blocks
static constexpr int QBLK = 128;    // q rows per workgroup (4 waves x 32)
static constexpr int KVB  = 64;     // kv rows per tile

static constexpr int KROW = 272;    // K_lds row stride bytes (136 bf16; 17 x 16B slots -> uniform banks)
static constexpr int VROW = 144;    // V_lds / P_lds row stride bytes (72 bf16; 9 x 16B slots)

typedef __attribute__((ext_vector_type(8)))  short   s16x8;
typedef __attribute__((ext_vector_type(8)))  __bf16  b16x8;
typedef __attribute__((ext_vector_type(16))) float   f32x16;

// ---- MFMA wrapper: compiles whether the builtin takes short8 or bf16x8 ----
template <typename T>
__device__ __forceinline__ auto mfma_try(T a, T b, f32x16 c, int)
    -> decltype(__builtin_amdgcn_mfma_f32_32x32x16_bf16(a, b, c, 0, 0, 0)) {
  return __builtin_amdgcn_mfma_f32_32x32x16_bf16(a, b, c, 0, 0, 0);
}
template <typename T>
__device__ __forceinline__ f32x16 mfma_try(T a, T b, f32x16 c, long) {
  using O = typename std::conditional<std::is_same<T, s16x8>::value, b16x8, s16x8>::type;
  return __builtin_amdgcn_mfma_f32_32x32x16_bf16(
      __builtin_bit_cast(O, a), __builtin_bit_cast(O, b), c, 0, 0, 0);
}
__device__ __forceinline__ f32x16 mfma32_bf16(s16x8 a, s16x8 b, f32x16 c) {
  return mfma_try(a, b, c, 0);
}

__device__ __forceinline__ short bfb(float x) {
  return (short)__builtin_bit_cast(unsigned short, (__bf16)x);
}
__device__ __forceinline__ unsigned pack_bf16x2(float a, float b) {
  unsigned ua = (unsigned short)__builtin_bit_cast(unsigned short, (__bf16)a);
  unsigned ub = (unsigned short)__builtin_bit_cast(unsigned short, (__bf16)b);
  return ua | (ub << 16);
}
__device__ __forceinline__ f32x16 zero16() {
  f32x16 z;
#pragma unroll
  for (int i = 0; i < 16; ++i) z[i] = 0.0f;
  return z;
}

// =====================================================================
// Kernel 1: paged KV-cache update. For every cache block, either copy the
// scattered key/value block (if its id appears in block_indices) or the
// original (zero) cache contents. Exact fp32 copy.
// =====================================================================
__global__ void __launch_bounds__(256)
cache_scatter_kernel(const float* __restrict__ k_in, const float* __restrict__ v_in,
                     const float* __restrict__ kc_in, const float* __restrict__ vc_in,
                     const int* __restrict__ bidx, int n_used,
                     float* __restrict__ kc_out, float* __restrict__ vc_out)
{
  const int BLK_ELEMS = PAGE * HKV * DD;   // 131072 floats per block
  const int wg    = blockIdx.x;
  const int chunk = wg & 7;                // 8 chunks per block copy
  const int which = (wg >> 3) & 1;         // 0 = key cache, 1 = value cache
  const int cb    = wg >> 4;               // cache block id 0..63

  int src_blk = -1;
  for (int i = 0; i < n_used; ++i)
    if (bidx[i] == cb) src_blk = i;        // last match wins (matches .at[].set)

  const float* src;
  float* dst;
  if (which == 0) {
    src = (src_blk >= 0) ? (k_in + (size_t)src_blk * BLK_ELEMS)
                         : (kc_in + (size_t)cb * BLK_ELEMS);
    dst = kc_out + (size_t)cb * BLK_ELEMS;
  } else {
    src = (src_blk >= 0) ? (v_in + (size_t)src_blk * BLK_ELEMS)
                         : (vc_in + (size_t)cb * BLK_ELEMS);
    dst = vc_out + (size_t)cb * BLK_ELEMS;
  }
  const int CHUNK = BLK_ELEMS / 8;         // 16384 floats
  const float4* s4 = (const float4*)(src + chunk * CHUNK);
  float4*       d4 = (float4*)(dst + chunk * CHUNK);
#pragma unroll 4
  for (int i = threadIdx.x; i < CHUNK / 4; i += 256) d4[i] = s4[i];
}

// =====================================================================
// Kernel 2: causal + ALiBi GQA prefill attention, bf16 MFMA 32x32x16.
// 1 wg = 4 waves; wave w owns 32 q rows. Swapped QK^T (S^T = K*Q^T) so
// each lane owns one q row (col = lane&31). PV as O^T = V^T * P^T with
// V staged transposed into LDS; P via wave-private padded LDS strip.
// =====================================================================
__global__ void __launch_bounds__(256, 2)
attn_kernel(const float* __restrict__ q_in, const float* __restrict__ k_in,
            const float* __restrict__ v_in, const float* __restrict__ slopes,
            float* __restrict__ out)
{
  __shared__ __align__(16) unsigned char K_lds[KVB * KROW];       // [kv][d]  bf16, 17408 B
  __shared__ __align__(16) unsigned char V_lds[DD * VROW];        // [d][kv]  bf16 (V^T), 18432 B
  __shared__ __align__(16) unsigned char P_lds[4 * 32 * VROW];    // per-wave [q][kv] bf16, 18432 B

  const int wgid = blockIdx.x;
  const int qt   = wgid & 7;
  const int g    = (wgid >> 3) & 3;
  const int hkv  = (wgid >> 5) & 7;
  const int b    = wgid >> 8;
  const int h    = hkv * GG + g;
  const int qb   = qt * QBLK;

  const int tid  = threadIdx.x;
  const int w    = tid >> 6;
  const int lane = tid & 63;
  const int ln   = lane & 31;
  const int hi   = lane >> 5;

  const float LOG2E  = 1.44269504088896340736f;
  const float QSCALE = 0.08838834764831845f * LOG2E;   // (1/sqrt(D)) * log2(e)
  const float slope2 = slopes[h] * LOG2E;

  const int qg = qb + w * 32 + ln;         // this lane's q row (col of S^T)

  // ---- Q fragments (B operand of every MFMA), pre-scaled, held in regs ----
  s16x8 qfrag[8];
  {
    const float* qrow = q_in + ((size_t)(b * SS + qg) * HH + h) * DD;
#pragma unroll
    for (int ks = 0; ks < 8; ++ks) {
      const float4 f0 = *(const float4*)(qrow + ks * 16 + hi * 8);
      const float4 f1 = *(const float4*)(qrow + ks * 16 + hi * 8 + 4);
      s16x8 qv;
      qv[0] = bfb(f0.x * QSCALE); qv[1] = bfb(f0.y * QSCALE);
      qv[2] = bfb(f0.z * QSCALE); qv[3] = bfb(f0.w * QSCALE);
      qv[4] = bfb(f1.x * QSCALE); qv[5] = bfb(f1.y * QSCALE);
      qv[6] = bfb(f1.z * QSCALE); qv[7] = bfb(f1.w * QSCALE);
      qfrag[ks] = qv;
    }
  }

  f32x16 acc[4];                            // O^T accum: 4 d-subtiles of 32
#pragma unroll
  for (int m = 0; m < 4; ++m) acc[m] = zero16();
  float mrun = -INFINITY, lrun = 0.0f;

  const int ntiles = 2 * qt + 2;            // causal: kv tiles 0 .. (qb+127)/64
  const int qwmax  = qb + w * 32 + 31;

  for (int t = 0; t < ntiles; ++t) {
    const int kvb = t * KVB;
    __syncthreads();

    // ---- stage K tile: [kv][d] bf16, 4 threads per row ----
    {
      const int kvr = tid >> 2, c = tid & 3;
      const float* src = k_in + ((size_t)(b * SS + kvb + kvr) * HKV + hkv) * DD + c * 32;
      unsigned char* dst = K_lds + kvr * KROW + c * 64;
#pragma unroll
      for (int j = 0; j < 4; ++j) {
        const float4 f0 = *(const float4*)(src + j * 8);
        const float4 f1 = *(const float4*)(src + j * 8 + 4);
        s16x8 kb;
        kb[0] = bfb(f0.x); kb[1] = bfb(f0.y); kb[2] = bfb(f0.z); kb[3] = bfb(f0.w);
        kb[4] = bfb(f1.x); kb[5] = bfb(f1.y); kb[6] = bfb(f1.z); kb[7] = bfb(f1.w);
        *(s16x8*)(dst + j * 16) = kb;
      }
    }
    // ---- stage V transposed: V_lds[d][kv]; thread owns a kv-pair x 16-d chunk ----
    {
      const int p = tid & 31, c2 = tid >> 5;
      const float* s0 = v_in + ((size_t)(b * SS + kvb + 2 * p) * HKV + hkv) * DD + c2 * 16;
      const float* s1 = s0 + HKV * DD;      // next kv row
      float ra[16], rb[16];
#pragma unroll
      for (int jj = 0; jj < 4; ++jj) {
        const float4 fa = *(const float4*)(s0 + jj * 4);
        const float4 fb = *(const float4*)(s1 + jj * 4);
        ra[jj*4+0] = fa.x; ra[jj*4+1] = fa.y; ra[jj*4+2] = fa.z; ra[jj*4+3] = fa.w;
        rb[jj*4+0] = fb.x; rb[jj*4+1] = fb.y; rb[jj*4+2] = fb.z; rb[jj*4+3] = fb.w;
      }
#pragma unroll
      for (int j = 0; j < 16; ++j)
        *(unsigned*)(V_lds + (c2 * 16 + j) * VROW + p * 4) = pack_bf16x2(ra[j], rb[j]);
    }
    __syncthreads();

    if (kvb > qwmax) continue;              // fully-masked for this wave (barriers stay uniform)

    // ---- S^T = K * Q^T : two 32-kv subtiles ----
    f32x16 sc[2];
#pragma unroll
    for (int kt = 0; kt < 2; ++kt) {
      f32x16 a = zero16();
      const unsigned char* krow = K_lds + (kt * 32 + ln) * KROW + hi * 16;
#pragma unroll
      for (int ks = 0; ks < 8; ++ks) {
        const s16x8 af = *(const s16x8*)(krow + ks * 32);
        a = mfma32_bf16(af, qfrag[ks], a);
      }
      sc[kt] = a;
    }

    // ---- ALiBi bias + causal mask + online softmax (log2 domain) ----
    float pm = -INFINITY;
#pragma unroll
    for (int kt = 0; kt < 2; ++kt) {
#pragma unroll
      for (int r = 0; r < 16; ++r) {
        const int kvg = kvb + kt * 32 + (r & 3) + 8 * (r >> 2) + 4 * hi;
        float lg = sc[kt][r] + slope2 * (float)(kvg - qg);
        lg = (kvg <= qg) ? lg : -INFINITY;
        sc[kt][r] = lg;
        pm = fmaxf(pm, lg);
      }
    }
    pm = fmaxf(pm, __shfl_xor(pm, 32));
    const float mnew = fmaxf(mrun, pm);
    const float fac  = __builtin_exp2f(mrun - mnew);   // first tile: exp2(-inf)=0
    float rs = 0.0f;
#pragma unroll
    for (int kt = 0; kt < 2; ++kt)
#pragma unroll
      for (int r = 0; r < 16; ++r) {
        const float pv = __builtin_exp2f(sc[kt][r] - mnew);
        sc[kt][r] = pv;
        rs += pv;
      }
    rs += __shfl_xor(rs, 32);
    lrun = lrun * fac + rs;
    mrun = mnew;
#pragma unroll
    for (int m = 0; m < 4; ++m)
#pragma unroll
      for (int r = 0; r < 16; ++r) acc[m][r] *= fac;

    // ---- P -> wave-private LDS strip (row = this lane's q) ----
    {
      unsigned char* pb = P_lds + (w * 32 + ln) * VROW;
#pragma unroll
      for (int kt = 0; kt < 2; ++kt)
#pragma unroll
        for (int j = 0; j < 8; ++j) {
          const int kv = kt * 32 + 8 * (j >> 1) + 4 * hi + 2 * (j & 1);
          *(unsigned*)(pb + kv * 2) = pack_bf16x2(sc[kt][2 * j], sc[kt][2 * j + 1]);
        }
    }

    // ---- O^T += V^T * P^T ----
#pragma unroll
    for (int ksv = 0; ksv < 4; ++ksv) {
      const s16x8 pfrag = *(const s16x8*)(P_lds + (w * 32 + ln) * VROW + ksv * 32 + hi * 16);
#pragma unroll
      for (int m = 0; m < 4; ++m) {
        const s16x8 vf = *(const s16x8*)(V_lds + (m * 32 + ln) * VROW + ksv * 32 + hi * 16);
        acc[m] = mfma32_bf16(vf, pfrag, acc[m]);
      }
    }
  }

  // ---- epilogue: O = O^T / l ----
  const float rinv = 1.0f / lrun;
  float* orow = out + ((size_t)(b * SS + qg) * HH + h) * DD;
#pragma unroll
  for (int m = 0; m < 4; ++m) {
#pragma unroll
    for (int rq = 0; rq < 4; ++rq) {
      float4 o;
      o.x = acc[m][4 * rq + 0] * rinv;
      o.y = acc[m][4 * rq + 1] * rinv;
      o.z = acc[m][4 * rq + 2] * rinv;
      o.w = acc[m][4 * rq + 3] * rinv;
      *(float4*)(orow + m * 32 + 8 * rq + 4 * hi) = o;
    }
  }
}

// =====================================================================
extern "C" void kernel_launch(void* const* d_in, const int* in_sizes, int n_in,
                              void* d_out, int out_size, void* d_ws, size_t ws_size,
                              hipStream_t stream)
{
  const float* query  = (const float*)d_in[0];
  const float* key    = (const float*)d_in[1];
  const float* value  = (const float*)d_in[2];
  const float* kc_in  = (const float*)d_in[3];
  const float* vc_in  = (const float*)d_in[4];
  const int*   bidx   = (const int*)d_in[5];
  const float* slopes = (const float*)d_in[6];
  const int n_used = in_sizes[5];

  float* out_attn = (float*)d_out;                               // [B,S,H*D]
  float* kc_out   = out_attn + (size_t)BB * SS * HH * DD;        // [64,128,8,128]
  float* vc_out   = kc_out + (size_t)NBLK * PAGE * HKV * DD;

  hipLaunchKernelGGL(cache_scatter_kernel, dim3(NBLK * 2 * 8), dim3(256), 0, stream,
                     key, value, kc_in, vc_in, bidx, n_used, kc_out, vc_out);
  hipLaunchKernelGGL(attn_kernel, dim3(BB * HKV * GG * (SS / QBLK)), dim3(256), 0, stream,
                     query, key, value, slopes, out_attn);
}

// Round 2
// 161.749 us; speedup vs baseline: 1.2726x; 1.2726x over previous
//
#include <hip/hip_runtime.h>
#include <hip/hip_bf16.h>
#include <type_traits>
#include <stdint.h>

// ---- problem constants ----
static constexpr int BB   = 4;
static constexpr int SS   = 1024;
static constexpr int HH   = 32;
static constexpr int HKV  = 8;
static constexpr int GG   = 4;      // H / HKV
static constexpr int DD   = 128;
static constexpr int PAGE = 128;    // paged-cache block size
static constexpr int NBLK = 64;     // cache blocks
static constexpr int QBLK = 128;    // q rows per q-tile (4 waves x 32)
static constexpr int KVB  = 64;     // kv rows per tile
static constexpr int KD   = HKV * DD;   // 1024 floats between kv rows

static constexpr int KROW = 272;    // K_lds row stride bytes (17 x 16B slots)
static constexpr int VROW = 144;    // V_lds row stride bytes (9 x 16B slots)

typedef __attribute__((ext_vector_type(8)))  short    s16x8;
typedef __attribute__((ext_vector_type(8)))  __bf16   b16x8;
typedef __attribute__((ext_vector_type(16))) float    f32x16;
typedef __attribute__((ext_vector_type(4)))  unsigned u32x4;

// ---- MFMA wrapper: compiles whether the builtin takes short8 or bf16x8 ----
template <typename T>
__device__ __forceinline__ auto mfma_try(T a, T b, f32x16 c, int)
    -> decltype(__builtin_amdgcn_mfma_f32_32x32x16_bf16(a, b, c, 0, 0, 0)) {
  return __builtin_amdgcn_mfma_f32_32x32x16_bf16(a, b, c, 0, 0, 0);
}
template <typename T>
__device__ __forceinline__ f32x16 mfma_try(T a, T b, f32x16 c, long) {
  using O = typename std::conditional<std::is_same<T, s16x8>::value, b16x8, s16x8>::type;
  return __builtin_amdgcn_mfma_f32_32x32x16_bf16(
      __builtin_bit_cast(O, a), __builtin_bit_cast(O, b), c, 0, 0, 0);
}
__device__ __forceinline__ f32x16 mfma32_bf16(s16x8 a, s16x8 b, f32x16 c) {
  return mfma_try(a, b, c, 0);
}

__device__ __forceinline__ short bfb(float x) {
  return (short)__builtin_bit_cast(unsigned short, (__bf16)x);
}
__device__ __forceinline__ unsigned pack_bf16x2(float a, float b) {
  unsigned ua = (unsigned short)__builtin_bit_cast(unsigned short, (__bf16)a);
  unsigned ub = (unsigned short)__builtin_bit_cast(unsigned short, (__bf16)b);
  return ua | (ub << 16);
}
__device__ __forceinline__ f32x16 zero16() {
  f32x16 z;
#pragma unroll
  for (int i = 0; i < 16; ++i) z[i] = 0.0f;
  return z;
}

// =====================================================================
// Kernel 1: paged KV-cache update (exact fp32 copy).
// =====================================================================
__global__ void __launch_bounds__(256)
cache_scatter_kernel(const float* __restrict__ k_in, const float* __restrict__ v_in,
                     const float* __restrict__ kc_in, const float* __restrict__ vc_in,
                     const int* __restrict__ bidx, int n_used,
                     float* __restrict__ kc_out, float* __restrict__ vc_out)
{
  const int BLK_ELEMS = PAGE * HKV * DD;   // 131072 floats per block
  const int wg    = blockIdx.x;
  const int chunk = wg & 7;
  const int which = (wg >> 3) & 1;
  const int cb    = wg >> 4;

  int src_blk = -1;
  for (int i = 0; i < n_used; ++i)
    if (bidx[i] == cb) src_blk = i;        // last match wins

  const float* src;
  float* dst;
  if (which == 0) {
    src = (src_blk >= 0) ? (k_in + (size_t)src_blk * BLK_ELEMS)
                         : (kc_in + (size_t)cb * BLK_ELEMS);
    dst = kc_out + (size_t)cb * BLK_ELEMS;
  } else {
    src = (src_blk >= 0) ? (v_in + (size_t)src_blk * BLK_ELEMS)
                         : (vc_in + (size_t)cb * BLK_ELEMS);
    dst = vc_out + (size_t)cb * BLK_ELEMS;
  }
  const int CHUNK = BLK_ELEMS / 8;
  const float4* s4 = (const float4*)(src + chunk * CHUNK);
  float4*       d4 = (float4*)(dst + chunk * CHUNK);
#pragma unroll 4
  for (int i = threadIdx.x; i < CHUNK / 4; i += 256) d4[i] = s4[i];
}

// =====================================================================
// Kernel 2: causal + ALiBi GQA prefill attention.
// wg = 4 waves; runs q-tiles (7-qtp) then (qtp) -> uniform 18 kv-tiles/wg.
// T14 async staging: issue tile t+1 global loads before compute of t,
// cvt+LDS-write after the barrier. P kept in registers (shfl_xor(32)).
// =====================================================================

#define VC(a, i) ((i)==0?(a).x:(i)==1?(a).y:(i)==2?(a).z:(a).w)

#define STAGE_LOAD(T) do {                                                       \
    const float* sk_ = k_in + ((bs_off + (T)*KVB + kvr)*HKV + hkv)*DD + c*32;    \
    kr0 = *(const float4*)(sk_+ 0); kr1 = *(const float4*)(sk_+ 4);              \
    kr2 = *(const float4*)(sk_+ 8); kr3 = *(const float4*)(sk_+12);              \
    kr4 = *(const float4*)(sk_+16); kr5 = *(const float4*)(sk_+20);              \
    kr6 = *(const float4*)(sk_+24); kr7 = *(const float4*)(sk_+28);              \
    const float* sv_ = v_in + ((bs_off + (T)*KVB + 2*p)*HKV + hkv)*DD + c2*16;   \
    vr0 = *(const float4*)(sv_+ 0);    vr1 = *(const float4*)(sv_+ 4);           \
    vr2 = *(const float4*)(sv_+ 8);    vr3 = *(const float4*)(sv_+12);           \
    vr4 = *(const float4*)(sv_+KD+0);  vr5 = *(const float4*)(sv_+KD+4);         \
    vr6 = *(const float4*)(sv_+KD+8);  vr7 = *(const float4*)(sv_+KD+12);        \
  } while(0)

#define KPACK(dst, lo, hi_)  do { s16x8 kb_;                                     \
    kb_[0]=bfb((lo).x); kb_[1]=bfb((lo).y); kb_[2]=bfb((lo).z); kb_[3]=bfb((lo).w); \
    kb_[4]=bfb((hi_).x); kb_[5]=bfb((hi_).y); kb_[6]=bfb((hi_).z); kb_[7]=bfb((hi_).w); \
    *(s16x8*)(dst) = kb_; } while(0)

#define STAGE_WRITE() do {                                                       \
    unsigned char* dk_ = K_lds + kvr*KROW + c*64;                                \
    KPACK(dk_ +  0, kr0, kr1); KPACK(dk_ + 16, kr2, kr3);                        \
    KPACK(dk_ + 32, kr4, kr5); KPACK(dk_ + 48, kr6, kr7);                        \
    unsigned char* dv_ = V_lds + (c2*16)*VROW + p*4;                             \
    _Pragma("unroll")                                                            \
    for (int j_ = 0; j_ < 16; ++j_) {                                            \
      const float lo_ = VC((j_>>2)==0?vr0:(j_>>2)==1?vr1:(j_>>2)==2?vr2:vr3, j_&3); \
      const float hi2_= VC((j_>>2)==0?vr4:(j_>>2)==1?vr5:(j_>>2)==2?vr6:vr7, j_&3); \
      *(unsigned*)(dv_ + j_*VROW) = pack_bf16x2(lo_, hi2_);                      \
    }                                                                            \
  } while(0)

__global__ void __launch_bounds__(256, 2)
attn_kernel(const float* __restrict__ q_in, const float* __restrict__ k_in,
            const float* __restrict__ v_in, const float* __restrict__ slopes,
            float* __restrict__ out)
{
  __shared__ __align__(16) unsigned char K_lds[KVB * KROW];   // [kv][d] bf16, 17408 B
  __shared__ __align__(16) unsigned char V_lds[DD * VROW];    // [d][kv] bf16 (V^T), 18432 B

  const int wgid0 = blockIdx.x;
  const int wgid  = ((wgid0 & 7) << 6) | (wgid0 >> 3);  // XCD-chunked swizzle (512 = 8*64)
  const int qtp = wgid & 3;
  const int g   = (wgid >> 2) & 3;
  const int hkv = (wgid >> 4) & 7;
  const int b   = wgid >> 7;
  const int h   = hkv * GG + g;

  const int tid  = threadIdx.x;
  const int w    = tid >> 6;
  const int lane = tid & 63;
  const int ln   = lane & 31;
  const int hi   = lane >> 5;

  const float LOG2E  = 1.44269504088896340736f;
  const float QSCALE = 0.08838834764831845f * LOG2E;
  const float slope2 = slopes[h] * LOG2E;

  // staging thread mapping (pass-invariant)
  const int kvr = tid >> 2, c  = tid & 3;   // K: row, 32-float col block
  const int p   = tid & 31, c2 = tid >> 5;  // V: kv-pair, 16-d col block

  const size_t bs_off = (size_t)b * SS;

  for (int pass = 0; pass < 2; ++pass) {
    const int qt    = pass ? qtp : (7 - qtp);
    const int qb    = qt * QBLK;
    const int qg    = qb + w * 32 + ln;
    const int qwmax = qb + w * 32 + 31;
    const int nt    = 2 * qt + 2;

    // ---- Q fragments, pre-scaled ----
    s16x8 qfrag[8];
    {
      const float* qrow = q_in + ((bs_off + qg) * HH + h) * DD;
#pragma unroll
      for (int ks = 0; ks < 8; ++ks) {
        const float4 f0 = *(const float4*)(qrow + ks * 16 + hi * 8);
        const float4 f1 = *(const float4*)(qrow + ks * 16 + hi * 8 + 4);
        s16x8 qv;
        qv[0] = bfb(f0.x * QSCALE); qv[1] = bfb(f0.y * QSCALE);
        qv[2] = bfb(f0.z * QSCALE); qv[3] = bfb(f0.w * QSCALE);
        qv[4] = bfb(f1.x * QSCALE); qv[5] = bfb(f1.y * QSCALE);
        qv[6] = bfb(f1.z * QSCALE); qv[7] = bfb(f1.w * QSCALE);
        qfrag[ks] = qv;
      }
    }

    f32x16 acc[4];
#pragma unroll
    for (int m = 0; m < 4; ++m) acc[m] = zero16();
    float mrun = -INFINITY, lrun = 0.0f;

    float4 kr0, kr1, kr2, kr3, kr4, kr5, kr6, kr7;
    float4 vr0, vr1, vr2, vr3, vr4, vr5, vr6, vr7;

    // ---- prologue: stage tile 0 ----
    __syncthreads();                 // prior pass's readers done
    STAGE_LOAD(0);
    STAGE_WRITE();
    __syncthreads();

    for (int t = 0; t < nt; ++t) {
      const int kvb = t * KVB;
      const bool pf = (t + 1 < nt);
      if (pf) STAGE_LOAD(t + 1);     // issue early; consumed after next barrier

      if (kvb <= qwmax) {
        // ---- S^T = K * Q^T ----
        f32x16 sc[2];
        __builtin_amdgcn_s_setprio(1);
#pragma unroll
        for (int kt = 0; kt < 2; ++kt) {
          f32x16 a = zero16();
          const unsigned char* krow = K_lds + (kt * 32 + ln) * KROW + hi * 16;
#pragma unroll
          for (int ks = 0; ks < 8; ++ks) {
            const s16x8 af = *(const s16x8*)(krow + ks * 32);
            a = mfma32_bf16(af, qfrag[ks], a);
          }
          sc[kt] = a;
        }
        __builtin_amdgcn_s_setprio(0);

        // ---- ALiBi + causal + online softmax (log2 domain) ----
        float pm = -INFINITY;
#pragma unroll
        for (int kt = 0; kt < 2; ++kt)
#pragma unroll
          for (int r = 0; r < 16; ++r) {
            const int kvg = kvb + kt * 32 + (r & 3) + 8 * (r >> 2) + 4 * hi;
            float lg = sc[kt][r] + slope2 * (float)(kvg - qg);
            lg = (kvg <= qg) ? lg : -INFINITY;
            sc[kt][r] = lg;
            pm = fmaxf(pm, lg);
          }
        pm = fmaxf(pm, __shfl_xor(pm, 32));
        const float mnew = fmaxf(mrun, pm);
        const float fac  = __builtin_exp2f(mrun - mnew);
        float rs = 0.0f;
        unsigned Wp[2][4][2];
#pragma unroll
        for (int kt = 0; kt < 2; ++kt) {
#pragma unroll
          for (int r = 0; r < 16; ++r) {
            const float pv = __builtin_exp2f(sc[kt][r] - mnew);
            sc[kt][r] = pv;
            rs += pv;
          }
#pragma unroll
          for (int m = 0; m < 4; ++m)
#pragma unroll
            for (int s = 0; s < 2; ++s)
              Wp[kt][m][s] = pack_bf16x2(sc[kt][4 * m + 2 * s], sc[kt][4 * m + 2 * s + 1]);
        }
        rs += __shfl_xor(rs, 32);
        lrun = lrun * fac + rs;
        mrun = mnew;
#pragma unroll
        for (int m = 0; m < 4; ++m)
#pragma unroll
          for (int r = 0; r < 16; ++r) acc[m][r] *= fac;

        // ---- O^T += V^T * P^T, P fragments built in-register ----
        __builtin_amdgcn_s_setprio(1);
#pragma unroll
        for (int ksv = 0; ksv < 4; ++ksv) {
          const int kt = ksv >> 1, k2 = ksv & 1;
          // hi-preselected exchange: one shfl serves both halves
          const unsigned a0 = hi ? Wp[kt][2 * k2][0] : Wp[kt][2 * k2 + 1][0];
          const unsigned a1 = hi ? Wp[kt][2 * k2][1] : Wp[kt][2 * k2 + 1][1];
          const unsigned x0 = __shfl_xor(a0, 32);
          const unsigned x1 = __shfl_xor(a1, 32);
          const unsigned f0 = hi ? x0 : Wp[kt][2 * k2][0];
          const unsigned f1 = hi ? x1 : Wp[kt][2 * k2][1];
          const unsigned f2 = hi ? Wp[kt][2 * k2 + 1][0] : x0;
          const unsigned f3 = hi ? Wp[kt][2 * k2 + 1][1] : x1;
          const u32x4 fw = {f0, f1, f2, f3};
          const s16x8 pfrag = __builtin_bit_cast(s16x8, fw);
#pragma unroll
          for (int m = 0; m < 4; ++m) {
            const s16x8 vf = *(const s16x8*)(V_lds + (m * 32 + ln) * VROW + ksv * 32 + hi * 16);
            acc[m] = mfma32_bf16(vf, pfrag, acc[m]);
          }
        }
        __builtin_amdgcn_s_setprio(0);
      }

      __syncthreads();               // all waves done reading tile t
      if (pf) STAGE_WRITE();         // cvt + write tile t+1 (vmcnt waits here)
      __syncthreads();
    }

    // ---- epilogue: O = O^T / l ----
    const float rinv = 1.0f / lrun;
    float* orow = out + ((bs_off + qg) * HH + h) * DD;
#pragma unroll
    for (int m = 0; m < 4; ++m)
#pragma unroll
      for (int rq = 0; rq < 4; ++rq) {
        float4 o;
        o.x = acc[m][4 * rq + 0] * rinv;
        o.y = acc[m][4 * rq + 1] * rinv;
        o.z = acc[m][4 * rq + 2] * rinv;
        o.w = acc[m][4 * rq + 3] * rinv;
        *(float4*)(orow + m * 32 + 8 * rq + 4 * hi) = o;
      }
  }
}

// =====================================================================
extern "C" void kernel_launch(void* const* d_in, const int* in_sizes, int n_in,
                              void* d_out, int out_size, void* d_ws, size_t ws_size,
                              hipStream_t stream)
{
  const float* query  = (const float*)d_in[0];
  const float* key    = (const float*)d_in[1];
  const float* value  = (const float*)d_in[2];
  const float* kc_in  = (const float*)d_in[3];
  const float* vc_in  = (const float*)d_in[4];
  const int*   bidx   = (const int*)d_in[5];
  const float* slopes = (const float*)d_in[6];
  const int n_used = in_sizes[5];

  float* out_attn = (float*)d_out;
  float* kc_out   = out_attn + (size_t)BB * SS * HH * DD;
  float* vc_out   = kc_out + (size_t)NBLK * PAGE * HKV * DD;

  hipLaunchKernelGGL(cache_scatter_kernel, dim3(NBLK * 2 * 8), dim3(256), 0, stream,
                     key, value, kc_in, vc_in, bidx, n_used, kc_out, vc_out);
  hipLaunchKernelGGL(attn_kernel, dim3(BB * HKV * GG * 4), dim3(256), 0, stream,
                     query, key, value, slopes, out_attn);
}